// Round 1
// baseline (275.502 us; speedup 1.0000x reference)
//
#include <hip/hip_runtime.h>
#include <math.h>

// ---------------------------------------------------------------------------
// HyperbolicInfoNCE on MI355X
//   inner = z1 @ diag(-1,1,...,1) @ z2^T   (8192 x 8192, K=129)
//   sims  = -acosh(max(-inner, 1+1e-6)) / 0.07
//   loss  = mean_b( 0.5*log(sum_k e^{sims[b,k]}) + 0.5*log(sum_k e^{sims[k,b]})
//                   - sims[b,b] )
// sims <= -0.02 < 0  =>  max-free sum of exp is safe in fp32.
// ---------------------------------------------------------------------------

#define BDIM   8192
#define K_IN   129
#define K_PAD  160      // 5 * 32
#define TILE   128
#define BK     32
#define NKT    (K_PAD / BK)   // 5

typedef __bf16  bf16x8 __attribute__((ext_vector_type(8)));
typedef float   f32x4  __attribute__((ext_vector_type(4)));

// ws layout (bytes)
#define OFF_A   0u
#define OFF_B   (BDIM * K_PAD * 2u)                  // 2,621,440
#define OFF_RS  (2u * BDIM * K_PAD * 2u)             // 5,242,880
#define OFF_CS  (OFF_RS + BDIM * 4u)
#define OFF_DG  (OFF_CS + BDIM * 4u)

__device__ __forceinline__ unsigned short f2bf_rne(float f) {
    unsigned int u = __float_as_uint(f);
    u += 0x7FFFu + ((u >> 16) & 1u);   // round-to-nearest-even
    return (unsigned short)(u >> 16);
}

// ---------------------------------------------------------------------------
// Kernel 1: fp32 -> bf16 conversion, K zero-padded 129->160, metric folded
// into A by negating column 0 of z1.
// ---------------------------------------------------------------------------
__global__ __launch_bounds__(256) void convert_kernel(
    const float* __restrict__ z1, const float* __restrict__ z2,
    unsigned short* __restrict__ A, unsigned short* __restrict__ B)
{
    int idx = blockIdx.x * 256 + threadIdx.x;
    if (idx >= BDIM * K_PAD) return;
    int r = idx / K_PAD;
    int c = idx - r * K_PAD;
    float va = 0.f, vb = 0.f;
    if (c < K_IN) {
        va = z1[r * K_IN + c];
        vb = z2[r * K_IN + c];
        if (c == 0) va = -va;          // Lorentz metric on first coordinate
    }
    A[idx] = f2bf_rne(va);
    B[idx] = f2bf_rne(vb);
}

// ---------------------------------------------------------------------------
// Kernel 2: 128x128-tile bf16 MFMA GEMM with fused acosh/exp epilogue and
// row/col partial-sum accumulation.
//   block = 256 threads = 4 waves, wave quadrant 64x64, 4x4 MFMA tiles
//   fragment layouts (guide-verified, m89/m91/m120):
//     A/B: elem [m=lane&15][k=(lane>>4)*8 + j]
//     C/D: elem [row=(lane>>4)*4 + reg][col=lane&15]
// ---------------------------------------------------------------------------
__global__ __launch_bounds__(256) void gemm_epilogue_kernel(
    const unsigned short* __restrict__ A, const unsigned short* __restrict__ B,
    float* __restrict__ row_sum, float* __restrict__ col_sum,
    float* __restrict__ diag)
{
    __shared__ __align__(16) unsigned short Alds[TILE * BK];
    __shared__ __align__(16) unsigned short Blds[TILE * BK];

    const int t    = threadIdx.x;
    const int lane = t & 63;
    const int wave = t >> 6;
    const int quad = lane >> 4;
    const int l16  = lane & 15;
    const int wr   = (wave >> 1) * 64;   // wave row offset in tile
    const int wc   = (wave & 1) * 64;    // wave col offset in tile
    const int rowBase = blockIdx.y * TILE;
    const int colBase = blockIdx.x * TILE;

    f32x4 acc[4][4] = {};

    for (int kt = 0; kt < NKT; ++kt) {
        // ---- stage 128x32 bf16 tiles of A and B into LDS ----
        uint4 va[2], vb[2];
        #pragma unroll
        for (int h = 0; h < 2; ++h) {
            int c  = t + h * 256;        // chunk id 0..511
            int r  = c >> 2;             // 0..127
            int ko = (c & 3) << 3;       // 0,8,16,24
            va[h] = *(const uint4*)(A + (rowBase + r) * K_PAD + kt * BK + ko);
            vb[h] = *(const uint4*)(B + (colBase + r) * K_PAD + kt * BK + ko);
        }
        __syncthreads();                 // previous iteration's reads done
        #pragma unroll
        for (int h = 0; h < 2; ++h) {
            int c  = t + h * 256;
            int r  = c >> 2;
            int ko = (c & 3) << 3;
            *(uint4*)&Alds[r * BK + ko] = va[h];
            *(uint4*)&Blds[r * BK + ko] = vb[h];
        }
        __syncthreads();

        // ---- fragments + 16 MFMA ----
        bf16x8 af[4], bfr[4];
        #pragma unroll
        for (int i = 0; i < 4; ++i) {
            af[i]  = *(const bf16x8*)&Alds[(wr + i * 16 + l16) * BK + quad * 8];
            bfr[i] = *(const bf16x8*)&Blds[(wc + i * 16 + l16) * BK + quad * 8];
        }
        #pragma unroll
        for (int i = 0; i < 4; ++i)
            #pragma unroll
            for (int j = 0; j < 4; ++j)
                acc[i][j] = __builtin_amdgcn_mfma_f32_16x16x32_bf16(
                                af[i], bfr[j], acc[i][j], 0, 0, 0);
    }

    // ---- fused epilogue: sims -> exp(sims), partial row/col sums ----
    // exp(sims) = u^(-1/0.07) = exp2(-14.2857142857 * log2(u)), u = x+sqrt(x^2-1)
    // sims      = -(ln2/0.07) * log2(u) = -9.902102579 * log2(u)
    const bool diagWave = (rowBase + wr) == (colBase + wc);
    float rowp[4][4] = {};
    float colp[4]    = {0.f, 0.f, 0.f, 0.f};

    #pragma unroll
    for (int i = 0; i < 4; ++i) {
        #pragma unroll
        for (int j = 0; j < 4; ++j) {
            #pragma unroll
            for (int reg = 0; reg < 4; ++reg) {
                float inner = acc[i][j][reg];
                float x = fmaxf(-inner, 1.000001f);
                float s = sqrtf(__builtin_fmaf(x, x, -1.0f));
                float l2u = log2f(x + s);
                float e = exp2f(-14.285714285714286f * l2u);
                rowp[i][reg] += e;
                colp[j]      += e;
                if (diagWave && i == j && (quad * 4 + reg) == l16) {
                    int R = rowBase + wr + i * 16 + quad * 4 + reg;
                    diag[R] = -9.902102579427789f * l2u;
                }
            }
        }
    }

    // row sums: reduce across the 16 lanes of each quad (they hold the 4 cols each)
    #pragma unroll
    for (int i = 0; i < 4; ++i) {
        #pragma unroll
        for (int reg = 0; reg < 4; ++reg) {
            float v = rowp[i][reg];
            v += __shfl_xor(v, 1);
            v += __shfl_xor(v, 2);
            v += __shfl_xor(v, 4);
            v += __shfl_xor(v, 8);
            if (l16 == 0)
                atomicAdd(&row_sum[rowBase + wr + i * 16 + quad * 4 + reg], v);
        }
    }
    // col sums: reduce across quads
    #pragma unroll
    for (int j = 0; j < 4; ++j) {
        float v = colp[j];
        v += __shfl_xor(v, 16);
        v += __shfl_xor(v, 32);
        if (quad == 0)
            atomicAdd(&col_sum[colBase + wc + j * 16 + l16], v);
    }
}

// ---------------------------------------------------------------------------
// Kernel 3: loss = mean_b( 0.5*ln(rs[b]) + 0.5*ln(cs[b]) - diag[b] )
// ---------------------------------------------------------------------------
__global__ __launch_bounds__(256) void finalize_kernel(
    const float* __restrict__ rs, const float* __restrict__ cs,
    const float* __restrict__ dg, float* __restrict__ out)
{
    __shared__ float part[4];
    int t = threadIdx.x;
    float a = 0.f;
    for (int b = t; b < BDIM; b += 256)
        a += 0.5f * (logf(rs[b]) + logf(cs[b])) - dg[b];
    #pragma unroll
    for (int m = 1; m < 64; m <<= 1) a += __shfl_xor(a, m);
    if ((t & 63) == 0) part[t >> 6] = a;
    __syncthreads();
    if (t == 0)
        out[0] = (part[0] + part[1] + part[2] + part[3]) * (1.0f / (float)BDIM);
}

// ---------------------------------------------------------------------------
extern "C" void kernel_launch(void* const* d_in, const int* in_sizes, int n_in,
                              void* d_out, int out_size, void* d_ws, size_t ws_size,
                              hipStream_t stream)
{
    const float* z1 = (const float*)d_in[0];
    const float* z2 = (const float*)d_in[1];
    float* out = (float*)d_out;

    char* ws = (char*)d_ws;
    unsigned short* A  = (unsigned short*)(ws + OFF_A);
    unsigned short* B  = (unsigned short*)(ws + OFF_B);
    float* row_sum     = (float*)(ws + OFF_RS);
    float* col_sum     = (float*)(ws + OFF_CS);
    float* diag        = (float*)(ws + OFF_DG);

    // zero row/col accumulators (ws is poisoned 0xAA before every call)
    hipMemsetAsync(ws + OFF_RS, 0, 2u * BDIM * 4u, stream);

    convert_kernel<<<(BDIM * K_PAD + 255) / 256, 256, 0, stream>>>(z1, z2, A, B);

    dim3 grid(BDIM / TILE, BDIM / TILE, 1);   // 64 x 64
    gemm_epilogue_kernel<<<grid, 256, 0, stream>>>(A, B, row_sum, col_sum, diag);

    finalize_kernel<<<1, 256, 0, stream>>>(row_sum, col_sum, diag, out);
}

// Round 2
// 226.563 us; speedup vs baseline: 1.2160x; 1.2160x over previous
//
#include <hip/hip_runtime.h>
#include <math.h>

// ---------------------------------------------------------------------------
// HyperbolicInfoNCE on MI355X — Round 2: barrier-free direct-from-global MFMA
//   inner = z1 @ diag(-1,1,...,1) @ z2^T   (8192 x 8192, K=129 padded to 160)
//   sims  = -acosh(max(-inner, 1+1e-6)) / 0.07
//   loss  = mean_b( 0.5*ln(sum_k e^{sims[b,k]}) + 0.5*ln(sum_k e^{sims[k,b]})
//                   - sims[b,b] )
// sims < 0 => max-free sum of exp is safe in fp32.
//
// R1 post-mortem: 5-iteration LDS-staged loop was barrier/latency-bound
// (MfmaUtil 4%, occupancy 22%). K is too short to amortize the m97 2-barrier
// structure. This round: no LDS, no __syncthreads — each wave loads its
// 16B-aligned MFMA fragments directly from global (L2-resident inputs),
// letting the compiler pipeline 40 loads against 80 MFMAs per wave.
// ---------------------------------------------------------------------------

#define BDIM   8192
#define K_IN   129
#define K_PAD  160      // 5 * 32
#define TILE   128
#define BK     32
#define NKT    (K_PAD / BK)   // 5

typedef __bf16  bf16x8 __attribute__((ext_vector_type(8)));
typedef float   f32x4  __attribute__((ext_vector_type(4)));

// ws layout (bytes)
#define OFF_A   0u
#define OFF_B   (BDIM * K_PAD * 2u)                  // 2,621,440
#define OFF_RS  (2u * BDIM * K_PAD * 2u)             // 5,242,880
#define OFF_CS  (OFF_RS + BDIM * 4u)
#define OFF_DG  (OFF_CS + BDIM * 4u)

__device__ __forceinline__ unsigned short f2bf_rne(float f) {
    unsigned int u = __float_as_uint(f);
    u += 0x7FFFu + ((u >> 16) & 1u);   // round-to-nearest-even
    return (unsigned short)(u >> 16);
}

// ---------------------------------------------------------------------------
// Kernel 1: fp32 -> bf16, K zero-padded 129->160, Lorentz metric folded into
// A by negating column 0 of z1. (LLVM strength-reduces /160 to mulhi.)
// ---------------------------------------------------------------------------
__global__ __launch_bounds__(256) void convert_kernel(
    const float* __restrict__ z1, const float* __restrict__ z2,
    unsigned short* __restrict__ A, unsigned short* __restrict__ B)
{
    int idx = blockIdx.x * 256 + threadIdx.x;
    if (idx >= BDIM * K_PAD) return;
    int r = idx / K_PAD;
    int c = idx - r * K_PAD;
    float va = 0.f, vb = 0.f;
    if (c < K_IN) {
        va = z1[r * K_IN + c];
        vb = z2[r * K_IN + c];
        if (c == 0) va = -va;          // Lorentz metric on first coordinate
    }
    A[idx] = f2bf_rne(va);
    B[idx] = f2bf_rne(vb);
}

// ---------------------------------------------------------------------------
// Kernel 2: 128x128-tile MFMA GEMM, fragments loaded DIRECTLY from global
// (no LDS, no barriers), fused acosh/exp epilogue + row/col partial sums.
//   block = 256 threads = 4 waves (2x2), wave tile 64x64, 4x4 MFMA 16x16x32
//   fragment layouts (guide-verified, m89/m91):
//     A/B: elem [m=lane&15][k=(lane>>4)*8 + j]
//     C/D: elem [row=(lane>>4)*4 + reg][col=lane&15]
//   A frag addr: (rowBase+wr+i*16+l16)*K_PAD + kt*32 + quad*8  -> 16B aligned
// ---------------------------------------------------------------------------
__global__ __launch_bounds__(256) void gemm_epilogue_kernel(
    const unsigned short* __restrict__ A, const unsigned short* __restrict__ B,
    float* __restrict__ row_sum, float* __restrict__ col_sum,
    float* __restrict__ diag)
{
    const int t    = threadIdx.x;
    const int lane = t & 63;
    const int wave = t >> 6;
    const int quad = lane >> 4;
    const int l16  = lane & 15;
    const int wr   = (wave >> 1) * 64;   // wave row offset in tile
    const int wc   = (wave & 1) * 64;    // wave col offset in tile
    const int rowBase = blockIdx.y * TILE;
    const int colBase = blockIdx.x * TILE;

    // per-lane fragment base pointers (row = ...+l16, col chunk = quad*8)
    const unsigned short* Abase = A + (rowBase + wr + l16) * K_PAD + quad * 8;
    const unsigned short* Bbase = B + (colBase + wc + l16) * K_PAD + quad * 8;

    f32x4 acc[4][4] = {};

    #pragma unroll
    for (int kt = 0; kt < NKT; ++kt) {
        bf16x8 af[4], bfr[4];
        #pragma unroll
        for (int i = 0; i < 4; ++i) {
            af[i]  = *(const bf16x8*)(Abase + i * 16 * K_PAD + kt * BK);
            bfr[i] = *(const bf16x8*)(Bbase + i * 16 * K_PAD + kt * BK);
        }
        #pragma unroll
        for (int i = 0; i < 4; ++i)
            #pragma unroll
            for (int j = 0; j < 4; ++j)
                acc[i][j] = __builtin_amdgcn_mfma_f32_16x16x32_bf16(
                                af[i], bfr[j], acc[i][j], 0, 0, 0);
    }

    // ---- fused epilogue ----
    // u = x + sqrt(x^2-1), x = max(-inner, 1+1e-6)
    // exp(sims) = u^(-1/0.07) = exp2(-14.2857142857 * log2(u))
    // sims      = -(ln2/0.07) * log2(u)
    const bool diagWave = (rowBase + wr) == (colBase + wc);
    float rowp[4][4] = {};
    float colp[4]    = {0.f, 0.f, 0.f, 0.f};

    #pragma unroll
    for (int i = 0; i < 4; ++i) {
        #pragma unroll
        for (int j = 0; j < 4; ++j) {
            #pragma unroll
            for (int reg = 0; reg < 4; ++reg) {
                float inner = acc[i][j][reg];
                float x = fmaxf(-inner, 1.000001f);
                float s = sqrtf(__builtin_fmaf(x, x, -1.0f));
                float l2u = log2f(x + s);
                float e = exp2f(-14.285714285714286f * l2u);
                rowp[i][reg] += e;
                colp[j]      += e;
                if (diagWave && i == j && (quad * 4 + reg) == l16) {
                    int R = rowBase + wr + i * 16 + quad * 4 + reg;
                    diag[R] = -9.902102579427789f * l2u;
                }
            }
        }
    }

    // row sums: reduce across the 16 lanes of each quad (they hold 4 cols each)
    #pragma unroll
    for (int i = 0; i < 4; ++i) {
        #pragma unroll
        for (int reg = 0; reg < 4; ++reg) {
            float v = rowp[i][reg];
            v += __shfl_xor(v, 1);
            v += __shfl_xor(v, 2);
            v += __shfl_xor(v, 4);
            v += __shfl_xor(v, 8);
            if (l16 == 0)
                atomicAdd(&row_sum[rowBase + wr + i * 16 + quad * 4 + reg], v);
        }
    }
    // col sums: reduce across quads
    #pragma unroll
    for (int j = 0; j < 4; ++j) {
        float v = colp[j];
        v += __shfl_xor(v, 16);
        v += __shfl_xor(v, 32);
        if (quad == 0)
            atomicAdd(&col_sum[colBase + wc + j * 16 + l16], v);
    }
}

// ---------------------------------------------------------------------------
// Kernel 3: loss = mean_b( 0.5*(ln rs[b] + ln cs[b]) - diag[b] )
// ---------------------------------------------------------------------------
__global__ __launch_bounds__(1024) void finalize_kernel(
    const float* __restrict__ rs, const float* __restrict__ cs,
    const float* __restrict__ dg, float* __restrict__ out)
{
    __shared__ float part[16];
    int t = threadIdx.x;
    float a = 0.f;
    for (int b = t; b < BDIM; b += 1024)
        a += 0.5f * (logf(rs[b]) + logf(cs[b])) - dg[b];
    #pragma unroll
    for (int m = 1; m < 64; m <<= 1) a += __shfl_xor(a, m);
    if ((t & 63) == 0) part[t >> 6] = a;
    __syncthreads();
    if (t < 16) {
        float v = part[t];
        #pragma unroll
        for (int m = 1; m < 16; m <<= 1) v += __shfl_xor(v, m);
        if (t == 0) out[0] = v * (1.0f / (float)BDIM);
    }
}

// ---------------------------------------------------------------------------
extern "C" void kernel_launch(void* const* d_in, const int* in_sizes, int n_in,
                              void* d_out, int out_size, void* d_ws, size_t ws_size,
                              hipStream_t stream)
{
    const float* z1 = (const float*)d_in[0];
    const float* z2 = (const float*)d_in[1];
    float* out = (float*)d_out;

    char* ws = (char*)d_ws;
    unsigned short* A  = (unsigned short*)(ws + OFF_A);
    unsigned short* B  = (unsigned short*)(ws + OFF_B);
    float* row_sum     = (float*)(ws + OFF_RS);
    float* col_sum     = (float*)(ws + OFF_CS);
    float* diag        = (float*)(ws + OFF_DG);

    // zero row/col accumulators (ws is poisoned 0xAA before every call)
    hipMemsetAsync(ws + OFF_RS, 0, 2u * BDIM * 4u, stream);

    convert_kernel<<<(BDIM * K_PAD + 255) / 256, 256, 0, stream>>>(z1, z2, A, B);

    dim3 grid(BDIM / TILE, BDIM / TILE, 1);   // 64 x 64
    gemm_epilogue_kernel<<<grid, 256, 0, stream>>>(A, B, row_sum, col_sum, diag);

    finalize_kernel<<<1, 1024, 0, stream>>>(row_sum, col_sum, diag, out);
}

// Round 3
// 194.991 us; speedup vs baseline: 1.4129x; 1.1619x over previous
//
#include <hip/hip_runtime.h>
#include <math.h>

// ---------------------------------------------------------------------------
// HyperbolicInfoNCE on MI355X — Round 3: hardware transcendentals
//   inner = z1 @ diag(-1,1,...,1) @ z2^T   (8192 x 8192, K=129 padded to 160)
//   sims  = -acosh(max(-inner, 1+1e-6)) / 0.07
//   loss  = mean_b( 0.5*ln(sum_k e^{sims[b,k]}) + 0.5*ln(sum_k e^{sims[k,b]})
//                   - sims[b,b] )
// sims < 0 => max-free sum of exp is safe in fp32.
//
// R2 post-mortem: 73 us of VALU issue = ocml library log2f/exp2f calls
// (~40 instrs each), not the predicted 15 us of raw v_log/v_exp/v_sqrt.
// This round: __builtin_amdgcn_{sqrtf,logf,exp2f} -> single quarter-rate
// instructions (v_sqrt_f32 / v_log_f32 [log2] / v_exp_f32 [2^x]).
// Also: memset folded into convert kernel; fast log in finalize.
// ---------------------------------------------------------------------------

#define BDIM   8192
#define K_IN   129
#define K_PAD  160      // 5 * 32
#define TILE   128
#define BK     32
#define NKT    (K_PAD / BK)   // 5

typedef __bf16  bf16x8 __attribute__((ext_vector_type(8)));
typedef float   f32x4  __attribute__((ext_vector_type(4)));

// ws layout (bytes)
#define OFF_A   0u
#define OFF_B   (BDIM * K_PAD * 2u)                  // 2,621,440
#define OFF_RS  (2u * BDIM * K_PAD * 2u)             // 5,242,880
#define OFF_CS  (OFF_RS + BDIM * 4u)
#define OFF_DG  (OFF_CS + BDIM * 4u)

// ---- hardware transcendentals (v_sqrt_f32 / v_log_f32 / v_exp_f32) ----
__device__ __forceinline__ float fast_sqrt(float x) {
#if __has_builtin(__builtin_amdgcn_sqrtf)
    return __builtin_amdgcn_sqrtf(x);
#else
    return sqrtf(x);
#endif
}
__device__ __forceinline__ float fast_log2(float x) {
#if __has_builtin(__builtin_amdgcn_logf)
    return __builtin_amdgcn_logf(x);       // log base 2
#else
    return __log2f(x);
#endif
}
__device__ __forceinline__ float fast_exp2(float x) {
#if __has_builtin(__builtin_amdgcn_exp2f)
    return __builtin_amdgcn_exp2f(x);      // 2^x
#else
    extern "C" __device__ float __ocml_native_exp2_f32(float);
    return __ocml_native_exp2_f32(x);
#endif
}

__device__ __forceinline__ unsigned short f2bf_rne(float f) {
    unsigned int u = __float_as_uint(f);
    u += 0x7FFFu + ((u >> 16) & 1u);   // round-to-nearest-even
    return (unsigned short)(u >> 16);
}

// ---------------------------------------------------------------------------
// Kernel 1: fp32 -> bf16, K zero-padded 129->160, Lorentz metric folded into
// A by negating column 0 of z1. Also zeroes row_sum/col_sum (ws is poisoned
// 0xAA before every call; rs and cs are contiguous).
// ---------------------------------------------------------------------------
__global__ __launch_bounds__(256) void convert_kernel(
    const float* __restrict__ z1, const float* __restrict__ z2,
    unsigned short* __restrict__ A, unsigned short* __restrict__ B,
    float* __restrict__ rs_cs)
{
    int idx = blockIdx.x * 256 + threadIdx.x;
    if (idx < 2 * BDIM) rs_cs[idx] = 0.f;
    if (idx >= BDIM * K_PAD) return;
    int r = idx / K_PAD;
    int c = idx - r * K_PAD;
    float va = 0.f, vb = 0.f;
    if (c < K_IN) {
        va = z1[r * K_IN + c];
        vb = z2[r * K_IN + c];
        if (c == 0) va = -va;          // Lorentz metric on first coordinate
    }
    A[idx] = f2bf_rne(va);
    B[idx] = f2bf_rne(vb);
}

// ---------------------------------------------------------------------------
// Kernel 2: 128x128-tile MFMA GEMM, fragments loaded DIRECTLY from global
// (no LDS, no barriers), fused acosh/exp epilogue + row/col partial sums.
//   block = 256 threads = 4 waves (2x2), wave tile 64x64, 4x4 MFMA 16x16x32
//   fragment layouts (guide-verified, m89/m91):
//     A/B: elem [m=lane&15][k=(lane>>4)*8 + j]
//     C/D: elem [row=(lane>>4)*4 + reg][col=lane&15]
// ---------------------------------------------------------------------------
__global__ __launch_bounds__(256) void gemm_epilogue_kernel(
    const unsigned short* __restrict__ A, const unsigned short* __restrict__ B,
    float* __restrict__ row_sum, float* __restrict__ col_sum,
    float* __restrict__ diag)
{
    const int t    = threadIdx.x;
    const int lane = t & 63;
    const int wave = t >> 6;
    const int quad = lane >> 4;
    const int l16  = lane & 15;
    const int wr   = (wave >> 1) * 64;   // wave row offset in tile
    const int wc   = (wave & 1) * 64;    // wave col offset in tile
    const int rowBase = blockIdx.y * TILE;
    const int colBase = blockIdx.x * TILE;

    const unsigned short* Abase = A + (rowBase + wr + l16) * K_PAD + quad * 8;
    const unsigned short* Bbase = B + (colBase + wc + l16) * K_PAD + quad * 8;

    f32x4 acc[4][4] = {};

    #pragma unroll
    for (int kt = 0; kt < NKT; ++kt) {
        bf16x8 af[4], bfr[4];
        #pragma unroll
        for (int i = 0; i < 4; ++i) {
            af[i]  = *(const bf16x8*)(Abase + i * 16 * K_PAD + kt * BK);
            bfr[i] = *(const bf16x8*)(Bbase + i * 16 * K_PAD + kt * BK);
        }
        #pragma unroll
        for (int i = 0; i < 4; ++i)
            #pragma unroll
            for (int j = 0; j < 4; ++j)
                acc[i][j] = __builtin_amdgcn_mfma_f32_16x16x32_bf16(
                                af[i], bfr[j], acc[i][j], 0, 0, 0);
    }

    // ---- fused epilogue ----
    // u = x + sqrt(x^2-1), x = max(-inner, 1+1e-6)
    // exp(sims) = u^(-1/0.07) = exp2(-14.2857142857 * log2(u))
    // sims      = -(ln2/0.07) * log2(u)
    const bool diagWave = (rowBase + wr) == (colBase + wc);
    float rowp[4][4] = {};
    float colp[4]    = {0.f, 0.f, 0.f, 0.f};

    #pragma unroll
    for (int i = 0; i < 4; ++i) {
        #pragma unroll
        for (int j = 0; j < 4; ++j) {
            #pragma unroll
            for (int reg = 0; reg < 4; ++reg) {
                float inner = acc[i][j][reg];
                float x = fmaxf(-inner, 1.000001f);
                float s = fast_sqrt(__builtin_fmaf(x, x, -1.0f));
                float l2u = fast_log2(x + s);
                float e = fast_exp2(-14.285714285714286f * l2u);
                rowp[i][reg] += e;
                colp[j]      += e;
                if (diagWave && i == j && (quad * 4 + reg) == l16) {
                    int R = rowBase + wr + i * 16 + quad * 4 + reg;
                    diag[R] = -9.902102579427789f * l2u;
                }
            }
        }
    }

    // row sums: reduce across the 16 lanes of each quad (they hold 4 cols each)
    #pragma unroll
    for (int i = 0; i < 4; ++i) {
        #pragma unroll
        for (int reg = 0; reg < 4; ++reg) {
            float v = rowp[i][reg];
            v += __shfl_xor(v, 1);
            v += __shfl_xor(v, 2);
            v += __shfl_xor(v, 4);
            v += __shfl_xor(v, 8);
            if (l16 == 0)
                atomicAdd(&row_sum[rowBase + wr + i * 16 + quad * 4 + reg], v);
        }
    }
    // col sums: reduce across quads
    #pragma unroll
    for (int j = 0; j < 4; ++j) {
        float v = colp[j];
        v += __shfl_xor(v, 16);
        v += __shfl_xor(v, 32);
        if (quad == 0)
            atomicAdd(&col_sum[colBase + wc + j * 16 + l16], v);
    }
}

// ---------------------------------------------------------------------------
// Kernel 3: loss = mean_b( 0.5*(ln rs[b] + ln cs[b]) - diag[b] )
// ln(v) = log2(v) * ln2
// ---------------------------------------------------------------------------
__global__ __launch_bounds__(1024) void finalize_kernel(
    const float* __restrict__ rs, const float* __restrict__ cs,
    const float* __restrict__ dg, float* __restrict__ out)
{
    __shared__ float part[16];
    int t = threadIdx.x;
    float a = 0.f;
    const float LN2_HALF = 0.34657359027997264f;  // 0.5 * ln2
    for (int b = t; b < BDIM; b += 1024)
        a += LN2_HALF * (fast_log2(rs[b]) + fast_log2(cs[b])) - dg[b];
    #pragma unroll
    for (int m = 1; m < 64; m <<= 1) a += __shfl_xor(a, m);
    if ((t & 63) == 0) part[t >> 6] = a;
    __syncthreads();
    if (t < 16) {
        float v = part[t];
        #pragma unroll
        for (int m = 1; m < 16; m <<= 1) v += __shfl_xor(v, m);
        if (t == 0) out[0] = v * (1.0f / (float)BDIM);
    }
}

// ---------------------------------------------------------------------------
extern "C" void kernel_launch(void* const* d_in, const int* in_sizes, int n_in,
                              void* d_out, int out_size, void* d_ws, size_t ws_size,
                              hipStream_t stream)
{
    const float* z1 = (const float*)d_in[0];
    const float* z2 = (const float*)d_in[1];
    float* out = (float*)d_out;

    char* ws = (char*)d_ws;
    unsigned short* A  = (unsigned short*)(ws + OFF_A);
    unsigned short* B  = (unsigned short*)(ws + OFF_B);
    float* row_sum     = (float*)(ws + OFF_RS);
    float* col_sum     = (float*)(ws + OFF_CS);
    float* diag        = (float*)(ws + OFF_DG);

    convert_kernel<<<(BDIM * K_PAD + 255) / 256, 256, 0, stream>>>(
        z1, z2, A, B, row_sum /* rs+cs contiguous */);

    dim3 grid(BDIM / TILE, BDIM / TILE, 1);   // 64 x 64
    gemm_epilogue_kernel<<<grid, 256, 0, stream>>>(A, B, row_sum, col_sum, diag);

    finalize_kernel<<<1, 1024, 0, stream>>>(row_sum, col_sum, diag, out);
}